// Round 9
// baseline (158.425 us; speedup 1.0000x reference)
//
#include <hip/hip_runtime.h>
#include <hip/hip_bf16.h>

typedef short s8v  __attribute__((ext_vector_type(8)));
typedef float f32x4 __attribute__((ext_vector_type(4)));
typedef unsigned int u32;
typedef u32 u32x4 __attribute__((ext_vector_type(4)));

#define NSLOT 31

// ---------- bf16 helpers (RNE) ----------
__device__ __forceinline__ unsigned short b16hi(float v) {
  unsigned int u = __float_as_uint(v);
  return (unsigned short)((u + 0x7FFFu + ((u >> 16) & 1u)) >> 16);
}
__device__ __forceinline__ float b16tof(unsigned short h) {
  return __uint_as_float(((unsigned int)h) << 16);
}
__device__ __forceinline__ unsigned short lobits(float w) {
  return b16hi(w - b16tof(b16hi(w)));
}
__device__ __forceinline__ float sp_stable(float v) {
  float ax = __builtin_fabsf(v);
  float e  = __expf(-ax);
  return fmaxf(v, 0.0f) + __logf(1.0f + e);
}
__device__ __forceinline__ float sigmoid_f(float v) {
  return __builtin_amdgcn_rcpf(1.0f + __expf(-v));
}

// =====================================================================
// PREP (identical to R6-R8, verified): A-frags for D = W . act^T
// lane l: m = l&15, k = 4*(l>>4)+{0..3} (dw0,1) and 16+4*(l>>4)+{0..3} (dw2,3)
// =====================================================================
struct P {
  const float *yW0,*yWs,*yb,*zW0,*zWs,*zb,*tW0,*tWs,*tb;
  const float *x0W,*x0b,*y0W,*y0b,*z0W,*z0b,*t0W,*t0b;
  const float *xWs,*xb,*xsW,*xsb,*xyW,*xyb,*xzW,*xzb,*xtW,*xtb,*fW,*fb;
};

__device__ unsigned short pat15(const float* W, const float* b, int k, int j, int sp) {
  if (k < 15)  { float v = W[j*15+k];      return b16hi(sp ? sp_stable(v) : v); }
  if (k == 15) return b ? b16hi(b[j]) : (unsigned short)0;
  if (k < 31)  { float v = W[j*15+(k-16)]; return lobits(sp ? sp_stable(v) : v); }
  return b ? lobits(b[j]) : (unsigned short)0;
}

__device__ unsigned short wA(int s, int k, int j, const P& p) {
  if (j > 14) return 0;
  if (s == 0) {
    if (k < 8)   return b16hi(sp_stable(p.yW0[j*8+k]));
    if (k < 16)  return lobits(sp_stable(p.yW0[j*8+(k-8)]));
    if (k == 16) return b16hi(p.yb[j]);
    if (k == 17) return lobits(p.yb[j]);
    return 0;
  }
  if (s <= 3)  return pat15(p.yWs + (s-1)*225, p.yb + s*15, k, j, 1);
  if (s == 4) {
    if (k < 8)   return b16hi(p.zW0[j*8+k]);
    if (k < 16)  return lobits(p.zW0[j*8+(k-8)]);
    if (k == 16) return b16hi(p.zb[j]);
    if (k == 17) return lobits(p.zb[j]);
    return 0;
  }
  if (s <= 7)  return pat15(p.zWs + (s-5)*225, p.zb + (s-4)*15, k, j, 0);
  if (s == 8) {
    if (k < 4)   return b16hi(sp_stable(p.tW0[j*4+k]));
    if (k < 8)   return lobits(sp_stable(p.tW0[j*4+(k-4)]));
    if (k == 8)  return b16hi(p.tb[j]);
    if (k == 9)  return lobits(p.tb[j]);
    return 0;
  }
  if (s <= 11) return pat15(p.tWs + (s-9)*225, p.tb + (s-8)*15, k, j, 1);
  if (s == 12) {
    if (k < 16) return b16hi(p.x0W[j*16+k]);
    return lobits(p.x0W[j*16+(k-16)]);
  }
  if (s == 13) {
    if (k < 8)  return b16hi(sp_stable(p.y0W[j*8+k]));
    if (k < 16) return b16hi(p.z0W[j*8+(k-8)]);
    if (k < 24) return lobits(sp_stable(p.y0W[j*8+(k-16)]));
    return lobits(p.z0W[j*8+(k-24)]);
  }
  if (s == 14) {
    if (k < 4)  return b16hi(sp_stable(p.t0W[j*4+k]));
    if (k < 8)  return lobits(sp_stable(p.t0W[j*4+(k-4)]));
    float xfb = p.x0b[j] + p.y0b[j] + p.z0b[j] + p.t0b[j];
    if (k == 8) return b16hi(xfb);
    if (k == 9) return lobits(xfb);
    return 0;
  }
  if (s <= 29) {
    int i = (s-15)/5, r = (s-15)%5;
    if (r == 0) {
      if (k == 15 || k == 31) {
        float xlb = p.xb[i*15+j] + p.xsb[i*15+j] + p.xyb[i*15+j]
                  + p.xzb[i*15+j] + p.xtb[i*15+j];
        return (k == 15) ? b16hi(xlb) : lobits(xlb);
      }
      return pat15(p.xWs + i*225, nullptr, k, j, 1);
    }
    if (r == 1) {
      const float* W = p.xsW + i*240;
      if (k < 16) return b16hi(W[j*16+k]);
      return lobits(W[j*16+(k-16)]);
    }
    if (r == 2) return pat15(p.xyW + i*225, nullptr, k, j, 1);
    if (r == 3) return pat15(p.xzW + i*225, nullptr, k, j, 0);
    return pat15(p.xtW + i*225, nullptr, k, j, 1);
  }
  return pat15(p.fW, p.fb, k, j, 0);   // s == 30
}

__global__ void prep_kernel(P p, u32* Abuf) {
  const int tid = blockIdx.x * blockDim.x + threadIdx.x;
  const int str = gridDim.x * blockDim.x;
  for (int idx = tid; idx < NSLOT*256; idx += str) {
    int s = idx >> 8, rem = idx & 255, l = rem >> 2, d = rem & 3;
    int g = l >> 4, j = l & 15;
    int kb = (d < 2) ? (4*g + 2*d) : (16 + 4*g + 2*(d-2));
    u32 v0 = wA(s, kb,   j, p);
    u32 v1 = wA(s, kb+1, j, p);
    Abuf[idx] = v0 | (v1 << 16);
  }
}

// =====================================================================
// MAIN: 1024-thread blocks -> 16 waves SHARE one 31 KiB LDS weight image.
// LDS/block = 51 KiB -> 2 blocks/CU -> 32 waves/CU (100% occupancy target);
// VGPR<=64 via __launch_bounds__(1024,8). Numerics identical to R6-R8.
// =====================================================================
union FragU { u32x4 u; s8v s; };
__device__ __forceinline__ s8v mkfrag(u32 a, u32 b, u32 c, u32 d) {
  FragU f; f.u = u32x4{a, b, c, d}; return f.s;
}
__device__ __forceinline__ u32 pk(float lo, float hi) {
  union { __hip_bfloat162 h; u32 u; } cv;
  cv.h = __float22bfloat162_rn(float2{lo, hi});
  return cv.u;
}
__device__ __forceinline__ float lo16f(u32 u) { return __uint_as_float(u << 16); }
__device__ __forceinline__ float hi16f(u32 u) { return __uint_as_float(u & 0xFFFF0000u); }

#define MFMA(A,B,C) __builtin_amdgcn_mfma_f32_16x16x32_bf16((A),(B),(C),0,0,0)
#define ONE2 0x3F803F80u

__device__ __forceinline__ void act_sp(f32x4 a, int g,
                                       u32& h0, u32& h1, u32& l0, u32& l1) {
  float v0 = sp_stable(a[0]), v1 = sp_stable(a[1]);
  float v2 = sp_stable(a[2]), v3 = sp_stable(a[3]);
  h0 = pk(v0, v1);
  u32 h1u = pk(v2, v3);
  l0 = pk(v0 - lo16f(h0),  v1 - hi16f(h0));
  l1 = pk(v2 - lo16f(h1u), v3 - hi16f(h1u));
  h1 = (g == 3) ? ((h1u & 0xFFFFu) | 0x3F800000u) : h1u;
  l1 = (g == 3) ? (l1 & 0xFFFFu) : l1;
}
__device__ __forceinline__ void act_sig(f32x4 a, int g, u32& d0, u32& d1) {
  d0 = pk(sigmoid_f(a[0]), sigmoid_f(a[1]));
  u32 d1u = pk(sigmoid_f(a[2]), sigmoid_f(a[3]));
  d1 = (g == 3) ? ((d1u & 0xFFFFu) | 0x3F800000u) : d1u;
}

#define NWAVE 16

__global__ __launch_bounds__(1024, 8) void isnn_fwd(
    const float* __restrict__ x0g, const float* __restrict__ y0g,
    const float* __restrict__ z0g, const float* __restrict__ t0g,
    const u32* __restrict__ Abuf, float* __restrict__ outg)
{
  __shared__ u32x4 wlds[NSLOT*64];        // 31 KiB weight frags (block-shared)
  __shared__ float olds[NWAVE][320];      // per-wave out staging (20 KiB)

  const int tid = threadIdx.x;
  // ---- stage weight frags into LDS once per block
  for (int i = tid; i < NSLOT*64; i += 1024) wlds[i] = ((const u32x4*)Abuf)[i];
  __syncthreads();

  const int lane = tid & 63;
  const int w    = tid >> 6;
  const int g    = lane >> 4;
  const int c    = lane & 15;

  // per-lane LDS base; AW(s) compiles to one ds_read_b128 with offset:s*1024
  const char* wbase = (const char*)wlds + lane * 16;
#define AW(s) (*(const s8v*)(wbase + (s)*1024))

  // ---- coalesced-store index precompute (240 floats per tile)
  int oidx[4]; bool oon[4];
#pragma unroll
  for (int jj = 0; jj < 4; ++jj) {
    int i = lane + 64*jj;
    oon[jj]  = (i < 240);
    int row  = i / 15, ch = i - row*15;
    oidx[jj] = row*20 + ch;
  }

  const int T0 = (blockIdx.x * NWAVE + w) * 4;
  const f32x4 zero4 = {0.f, 0.f, 0.f, 0.f};

  // ---- input regs (tile prefetch pipeline); wave reads 1KiB contiguous
  float4 x4 = ((const float4*)x0g)[(size_t)(T0*16 + c)*4 + g];
  float4 y4 = ((const float4*)y0g)[(size_t)(T0*16 + c)*2 + (g & 1)];
  float4 z4 = ((const float4*)z0g)[(size_t)(T0*16 + c)*2 + (g & 1)];
  float4 t4 = ((const float4*)t0g)[(size_t)(T0*16 + c)];

#pragma unroll
  for (int it = 0; it < 4; ++it) {
    const int T = T0 + it;

    // ---- build input B-frags
    u32 dx0 = pk(x4.x, x4.y), dx1 = pk(x4.z, x4.w);
    u32 dy0 = pk(y4.x, y4.y), dy1 = pk(y4.z, y4.w);
    u32 dz0 = pk(z4.x, z4.y), dz1 = pk(z4.z, z4.w);
    u32 dt0 = pk(t4.x, t4.y), dt1 = pk(t4.z, t4.w);
    u32 bsl = (g == 0) ? ONE2 : 0u;
    s8v Bx0 = mkfrag(dx0, dx1, dx0, dx1);
    s8v By0 = mkfrag(dy0, dy1, bsl, 0u);
    s8v Bz0 = mkfrag(dz0, dz1, bsl, 0u);
    s8v Bt0 = mkfrag((g < 2) ? dt0 : ((g == 2) ? ONE2 : 0u),
                     (g < 2) ? dt1 : 0u, 0u, 0u);
    u32 syz0 = (g < 2) ? dy0 : dz0, syz1 = (g < 2) ? dy1 : dz1;
    s8v Byz = mkfrag(syz0, syz1, syz0, syz1);

    // ---- prefetch next tile's inputs
    if (it < 3) {
      x4 = ((const float4*)x0g)[(size_t)((T+1)*16 + c)*4 + g];
      y4 = ((const float4*)y0g)[(size_t)((T+1)*16 + c)*2 + (g & 1)];
      z4 = ((const float4*)z0g)[(size_t)((T+1)*16 + c)*2 + (g & 1)];
      t4 = ((const float4*)t0g)[(size_t)((T+1)*16 + c)];
    }

    // ---- towers layer 1
    f32x4 aY = MFMA(AW(0), By0, zero4);
    f32x4 aZ = MFMA(AW(4), Bz0, zero4);
    f32x4 aT = MFMA(AW(8), Bt0, zero4);

    // ---- towers layers 2..4
    u32 yh0, yh1, yl0, yl1, zf0, zf1, tf0, tf1;
#pragma unroll
    for (int l = 0; l < 3; ++l) {
      act_sp(aY, g, yh0, yh1, yl0, yl1);
      act_sig(aZ, g, zf0, zf1);
      act_sig(aT, g, tf0, tf1);
      s8v ay = AW(1+l);
      aY = MFMA(ay, mkfrag(yh0, yh1, yh0, yh1), zero4);
      aY = MFMA(ay, mkfrag(yl0, yl1, 0u, 0u), aY);
      aZ = MFMA(AW(5+l), mkfrag(zf0, zf1, zf0, zf1), zero4);
      aT = MFMA(AW(9+l), mkfrag(tf0, tf1, tf0, tf1), zero4);
    }
    act_sp(aY, g, yh0, yh1, yl0, yl1);
    act_sig(aZ, g, zf0, zf1);
    act_sig(aT, g, tf0, tf1);
    s8v FyH = mkfrag(yh0, yh1, yh0, yh1);
    s8v FyL = mkfrag(yl0, yl1, 0u, 0u);
    s8v Fz  = mkfrag(zf0, zf1, zf0, zf1);
    s8v Ft  = mkfrag(tf0, tf1, tf0, tf1);

    // ---- x first block
    f32x4 aX = MFMA(AW(12), Bx0, zero4);
    aX = MFMA(AW(13), Byz, aX);
    aX = MFMA(AW(14), Bt0, aX);

    // ---- 3 x iterations
    u32 xh0, xh1, xl0, xl1;
#pragma unroll
    for (int i = 0; i < 3; ++i) {
      act_sp(aX, g, xh0, xh1, xl0, xl1);
      s8v ax = AW(15+5*i);
      aX = MFMA(ax, mkfrag(xh0, xh1, xh0, xh1), zero4);
      aX = MFMA(ax, mkfrag(xl0, xl1, 0u, 0u), aX);
      aX = MFMA(AW(16+5*i), Bx0, aX);
      s8v axy = AW(17+5*i);
      aX = MFMA(axy, FyH, aX);
      aX = MFMA(axy, FyL, aX);
      aX = MFMA(AW(18+5*i), Fz, aX);
      aX = MFMA(AW(19+5*i), Ft, aX);
    }

    // ---- final linear
    act_sp(aX, g, xh0, xh1, xl0, xl1);
    s8v af = AW(30);
    f32x4 aO = MFMA(af, mkfrag(xh0, xh1, xh0, xh1), zero4);
    aO = MFMA(af, mkfrag(xl0, xl1, 0u, 0u), aO);

    // ---- coalesced store via tiny LDS transpose
    *(f32x4*)(&olds[w][c*20 + 4*g]) = aO;
    float* orow = outg + (size_t)T * 240;
#pragma unroll
    for (int jj = 0; jj < 4; ++jj)
      if (oon[jj]) orow[lane + 64*jj] = olds[w][oidx[jj]];
  }
#undef AW
}

extern "C" void kernel_launch(void* const* d_in, const int* in_sizes, int n_in,
                              void* d_out, int out_size, void* d_ws, size_t ws_size,
                              hipStream_t stream) {
  P p;
  p.yW0 = (const float*)d_in[4];  p.yWs = (const float*)d_in[5];  p.yb  = (const float*)d_in[6];
  p.zW0 = (const float*)d_in[7];  p.zWs = (const float*)d_in[8];  p.zb  = (const float*)d_in[9];
  p.tW0 = (const float*)d_in[10]; p.tWs = (const float*)d_in[11]; p.tb  = (const float*)d_in[12];
  p.x0W = (const float*)d_in[13]; p.x0b = (const float*)d_in[14];
  p.y0W = (const float*)d_in[15]; p.y0b = (const float*)d_in[16];
  p.z0W = (const float*)d_in[17]; p.z0b = (const float*)d_in[18];
  p.t0W = (const float*)d_in[19]; p.t0b = (const float*)d_in[20];
  p.xWs = (const float*)d_in[21]; p.xb  = (const float*)d_in[22];
  p.xsW = (const float*)d_in[23]; p.xsb = (const float*)d_in[24];
  p.xyW = (const float*)d_in[25]; p.xyb = (const float*)d_in[26];
  p.xzW = (const float*)d_in[27]; p.xzb = (const float*)d_in[28];
  p.xtW = (const float*)d_in[29]; p.xtb = (const float*)d_in[30];
  p.fW  = (const float*)d_in[31]; p.fb  = (const float*)d_in[32];

  u32* Abuf = (u32*)d_ws;
  prep_kernel<<<8, 256, 0, stream>>>(p, Abuf);

  const float* x0 = (const float*)d_in[0];
  const float* y0 = (const float*)d_in[1];
  const float* z0 = (const float*)d_in[2];
  const float* t0 = (const float*)d_in[3];

  const int n = in_sizes[0] / 16;          // 1048576 rows
  const int blocks = n / 1024;             // 16 waves x 4 tiles x 16 rows
  isnn_fwd<<<blocks, 1024, 0, stream>>>(x0, y0, z0, t0, Abuf, (float*)d_out);
}

// Round 10
// 143.665 us; speedup vs baseline: 1.1027x; 1.1027x over previous
//
#include <hip/hip_runtime.h>
#include <hip/hip_bf16.h>

typedef short s8v  __attribute__((ext_vector_type(8)));
typedef float f32x4 __attribute__((ext_vector_type(4)));
typedef unsigned int u32;
typedef u32 u32x4 __attribute__((ext_vector_type(4)));

#define NSLOT 31

// ---------- bf16 helpers (RNE) ----------
__device__ __forceinline__ unsigned short b16hi(float v) {
  unsigned int u = __float_as_uint(v);
  return (unsigned short)((u + 0x7FFFu + ((u >> 16) & 1u)) >> 16);
}
__device__ __forceinline__ float b16tof(unsigned short h) {
  return __uint_as_float(((unsigned int)h) << 16);
}
__device__ __forceinline__ unsigned short lobits(float w) {
  return b16hi(w - b16tof(b16hi(w)));
}
__device__ __forceinline__ float sp_stable(float v) {
  float ax = __builtin_fabsf(v);
  float e  = __expf(-ax);
  return fmaxf(v, 0.0f) + __logf(1.0f + e);
}
__device__ __forceinline__ float sigmoid_f(float v) {
  return __builtin_amdgcn_rcpf(1.0f + __expf(-v));
}

// =====================================================================
// PREP (identical to R6-R9, verified): A-frags for D = W . act^T
// lane l: m = l&15, k = 4*(l>>4)+{0..3} (dw0,1) and 16+4*(l>>4)+{0..3} (dw2,3)
// =====================================================================
struct P {
  const float *yW0,*yWs,*yb,*zW0,*zWs,*zb,*tW0,*tWs,*tb;
  const float *x0W,*x0b,*y0W,*y0b,*z0W,*z0b,*t0W,*t0b;
  const float *xWs,*xb,*xsW,*xsb,*xyW,*xyb,*xzW,*xzb,*xtW,*xtb,*fW,*fb;
};

__device__ unsigned short pat15(const float* W, const float* b, int k, int j, int sp) {
  if (k < 15)  { float v = W[j*15+k];      return b16hi(sp ? sp_stable(v) : v); }
  if (k == 15) return b ? b16hi(b[j]) : (unsigned short)0;
  if (k < 31)  { float v = W[j*15+(k-16)]; return lobits(sp ? sp_stable(v) : v); }
  return b ? lobits(b[j]) : (unsigned short)0;
}

__device__ unsigned short wA(int s, int k, int j, const P& p) {
  if (j > 14) return 0;
  if (s == 0) {
    if (k < 8)   return b16hi(sp_stable(p.yW0[j*8+k]));
    if (k < 16)  return lobits(sp_stable(p.yW0[j*8+(k-8)]));
    if (k == 16) return b16hi(p.yb[j]);
    if (k == 17) return lobits(p.yb[j]);
    return 0;
  }
  if (s <= 3)  return pat15(p.yWs + (s-1)*225, p.yb + s*15, k, j, 1);
  if (s == 4) {
    if (k < 8)   return b16hi(p.zW0[j*8+k]);
    if (k < 16)  return lobits(p.zW0[j*8+(k-8)]);
    if (k == 16) return b16hi(p.zb[j]);
    if (k == 17) return lobits(p.zb[j]);
    return 0;
  }
  if (s <= 7)  return pat15(p.zWs + (s-5)*225, p.zb + (s-4)*15, k, j, 0);
  if (s == 8) {
    if (k < 4)   return b16hi(sp_stable(p.tW0[j*4+k]));
    if (k < 8)   return lobits(sp_stable(p.tW0[j*4+(k-4)]));
    if (k == 8)  return b16hi(p.tb[j]);
    if (k == 9)  return lobits(p.tb[j]);
    return 0;
  }
  if (s <= 11) return pat15(p.tWs + (s-9)*225, p.tb + (s-8)*15, k, j, 1);
  if (s == 12) {
    if (k < 16) return b16hi(p.x0W[j*16+k]);
    return lobits(p.x0W[j*16+(k-16)]);
  }
  if (s == 13) {
    if (k < 8)  return b16hi(sp_stable(p.y0W[j*8+k]));
    if (k < 16) return b16hi(p.z0W[j*8+(k-8)]);
    if (k < 24) return lobits(sp_stable(p.y0W[j*8+(k-16)]));
    return lobits(p.z0W[j*8+(k-24)]);
  }
  if (s == 14) {
    if (k < 4)  return b16hi(sp_stable(p.t0W[j*4+k]));
    if (k < 8)  return lobits(sp_stable(p.t0W[j*4+(k-4)]));
    float xfb = p.x0b[j] + p.y0b[j] + p.z0b[j] + p.t0b[j];
    if (k == 8) return b16hi(xfb);
    if (k == 9) return lobits(xfb);
    return 0;
  }
  if (s <= 29) {
    int i = (s-15)/5, r = (s-15)%5;
    if (r == 0) {
      if (k == 15 || k == 31) {
        float xlb = p.xb[i*15+j] + p.xsb[i*15+j] + p.xyb[i*15+j]
                  + p.xzb[i*15+j] + p.xtb[i*15+j];
        return (k == 15) ? b16hi(xlb) : lobits(xlb);
      }
      return pat15(p.xWs + i*225, nullptr, k, j, 1);
    }
    if (r == 1) {
      const float* W = p.xsW + i*240;
      if (k < 16) return b16hi(W[j*16+k]);
      return lobits(W[j*16+(k-16)]);
    }
    if (r == 2) return pat15(p.xyW + i*225, nullptr, k, j, 1);
    if (r == 3) return pat15(p.xzW + i*225, nullptr, k, j, 0);
    return pat15(p.xtW + i*225, nullptr, k, j, 1);
  }
  return pat15(p.fW, p.fb, k, j, 0);   // s == 30
}

__global__ void prep_kernel(P p, u32* Abuf) {
  const int tid = blockIdx.x * blockDim.x + threadIdx.x;
  const int str = gridDim.x * blockDim.x;
  for (int idx = tid; idx < NSLOT*256; idx += str) {
    int s = idx >> 8, rem = idx & 255, l = rem >> 2, d = rem & 3;
    int g = l >> 4, j = l & 15;
    int kb = (d < 2) ? (4*g + 2*d) : (16 + 4*g + 2*(d-2));
    u32 v0 = wA(s, kb,   j, p);
    u32 v1 = wA(s, kb+1, j, p);
    Abuf[idx] = v0 | (v1 << 16);
  }
}

// =====================================================================
// MAIN: 512-thread blocks (8 waves share one 31 KiB LDS weight image).
// LDS/block = 42 KiB -> 3 blocks/CU -> 6 waves/SIMD (75% occupancy);
// __launch_bounds__(512,6) -> 85-reg total budget >= ~84 the body needs
// (R9 lesson: (1024,8)'s 64-reg budget spilled; 1024-blocks can only hit
// 4 or 8 waves/SIMD, so 512 is the unique spill-free 6-wave geometry).
// Numerics identical to R6-R9.
// =====================================================================
union FragU { u32x4 u; s8v s; };
__device__ __forceinline__ s8v mkfrag(u32 a, u32 b, u32 c, u32 d) {
  FragU f; f.u = u32x4{a, b, c, d}; return f.s;
}
__device__ __forceinline__ u32 pk(float lo, float hi) {
  union { __hip_bfloat162 h; u32 u; } cv;
  cv.h = __float22bfloat162_rn(float2{lo, hi});
  return cv.u;
}
__device__ __forceinline__ float lo16f(u32 u) { return __uint_as_float(u << 16); }
__device__ __forceinline__ float hi16f(u32 u) { return __uint_as_float(u & 0xFFFF0000u); }

#define MFMA(A,B,C) __builtin_amdgcn_mfma_f32_16x16x32_bf16((A),(B),(C),0,0,0)
#define ONE2 0x3F803F80u

__device__ __forceinline__ void act_sp(f32x4 a, int g,
                                       u32& h0, u32& h1, u32& l0, u32& l1) {
  float v0 = sp_stable(a[0]), v1 = sp_stable(a[1]);
  float v2 = sp_stable(a[2]), v3 = sp_stable(a[3]);
  h0 = pk(v0, v1);
  u32 h1u = pk(v2, v3);
  l0 = pk(v0 - lo16f(h0),  v1 - hi16f(h0));
  l1 = pk(v2 - lo16f(h1u), v3 - hi16f(h1u));
  h1 = (g == 3) ? ((h1u & 0xFFFFu) | 0x3F800000u) : h1u;
  l1 = (g == 3) ? (l1 & 0xFFFFu) : l1;
}
__device__ __forceinline__ void act_sig(f32x4 a, int g, u32& d0, u32& d1) {
  d0 = pk(sigmoid_f(a[0]), sigmoid_f(a[1]));
  u32 d1u = pk(sigmoid_f(a[2]), sigmoid_f(a[3]));
  d1 = (g == 3) ? ((d1u & 0xFFFFu) | 0x3F800000u) : d1u;
}

#define NWAVE 8

__global__ __launch_bounds__(512, 6) void isnn_fwd(
    const float* __restrict__ x0g, const float* __restrict__ y0g,
    const float* __restrict__ z0g, const float* __restrict__ t0g,
    const u32* __restrict__ Abuf, float* __restrict__ outg)
{
  __shared__ u32x4 wlds[NSLOT*64];        // 31 KiB weight frags (block-shared)
  __shared__ float olds[NWAVE][320];      // per-wave out staging (10 KiB)

  const int tid = threadIdx.x;
  // ---- stage weight frags into LDS once per block
  for (int i = tid; i < NSLOT*64; i += 512) wlds[i] = ((const u32x4*)Abuf)[i];
  __syncthreads();

  const int lane = tid & 63;
  const int w    = tid >> 6;
  const int g    = lane >> 4;
  const int c    = lane & 15;

  // per-lane LDS base; AW(s) compiles to one ds_read_b128 with offset:s*1024
  const char* wbase = (const char*)wlds + lane * 16;
#define AW(s) (*(const s8v*)(wbase + (s)*1024))

  // ---- coalesced-store index precompute (240 floats per tile)
  int oidx[4]; bool oon[4];
#pragma unroll
  for (int jj = 0; jj < 4; ++jj) {
    int i = lane + 64*jj;
    oon[jj]  = (i < 240);
    int row  = i / 15, ch = i - row*15;
    oidx[jj] = row*20 + ch;
  }

  const int T0 = (blockIdx.x * NWAVE + w) * 4;
  const f32x4 zero4 = {0.f, 0.f, 0.f, 0.f};

  // ---- input regs (tile prefetch pipeline); wave reads 1KiB contiguous
  float4 x4 = ((const float4*)x0g)[(size_t)(T0*16 + c)*4 + g];
  float4 y4 = ((const float4*)y0g)[(size_t)(T0*16 + c)*2 + (g & 1)];
  float4 z4 = ((const float4*)z0g)[(size_t)(T0*16 + c)*2 + (g & 1)];
  float4 t4 = ((const float4*)t0g)[(size_t)(T0*16 + c)];

#pragma unroll
  for (int it = 0; it < 4; ++it) {
    const int T = T0 + it;

    // ---- build input B-frags
    u32 dx0 = pk(x4.x, x4.y), dx1 = pk(x4.z, x4.w);
    u32 dy0 = pk(y4.x, y4.y), dy1 = pk(y4.z, y4.w);
    u32 dz0 = pk(z4.x, z4.y), dz1 = pk(z4.z, z4.w);
    u32 dt0 = pk(t4.x, t4.y), dt1 = pk(t4.z, t4.w);
    u32 bsl = (g == 0) ? ONE2 : 0u;
    s8v Bx0 = mkfrag(dx0, dx1, dx0, dx1);
    s8v By0 = mkfrag(dy0, dy1, bsl, 0u);
    s8v Bz0 = mkfrag(dz0, dz1, bsl, 0u);
    s8v Bt0 = mkfrag((g < 2) ? dt0 : ((g == 2) ? ONE2 : 0u),
                     (g < 2) ? dt1 : 0u, 0u, 0u);
    u32 syz0 = (g < 2) ? dy0 : dz0, syz1 = (g < 2) ? dy1 : dz1;
    s8v Byz = mkfrag(syz0, syz1, syz0, syz1);

    // ---- prefetch next tile's inputs
    if (it < 3) {
      x4 = ((const float4*)x0g)[(size_t)((T+1)*16 + c)*4 + g];
      y4 = ((const float4*)y0g)[(size_t)((T+1)*16 + c)*2 + (g & 1)];
      z4 = ((const float4*)z0g)[(size_t)((T+1)*16 + c)*2 + (g & 1)];
      t4 = ((const float4*)t0g)[(size_t)((T+1)*16 + c)];
    }

    // ---- towers layer 1
    f32x4 aY = MFMA(AW(0), By0, zero4);
    f32x4 aZ = MFMA(AW(4), Bz0, zero4);
    f32x4 aT = MFMA(AW(8), Bt0, zero4);

    // ---- towers layers 2..4
    u32 yh0, yh1, yl0, yl1, zf0, zf1, tf0, tf1;
#pragma unroll
    for (int l = 0; l < 3; ++l) {
      act_sp(aY, g, yh0, yh1, yl0, yl1);
      act_sig(aZ, g, zf0, zf1);
      act_sig(aT, g, tf0, tf1);
      s8v ay = AW(1+l);
      aY = MFMA(ay, mkfrag(yh0, yh1, yh0, yh1), zero4);
      aY = MFMA(ay, mkfrag(yl0, yl1, 0u, 0u), aY);
      aZ = MFMA(AW(5+l), mkfrag(zf0, zf1, zf0, zf1), zero4);
      aT = MFMA(AW(9+l), mkfrag(tf0, tf1, tf0, tf1), zero4);
    }
    act_sp(aY, g, yh0, yh1, yl0, yl1);
    act_sig(aZ, g, zf0, zf1);
    act_sig(aT, g, tf0, tf1);
    s8v FyH = mkfrag(yh0, yh1, yh0, yh1);
    s8v FyL = mkfrag(yl0, yl1, 0u, 0u);
    s8v Fz  = mkfrag(zf0, zf1, zf0, zf1);
    s8v Ft  = mkfrag(tf0, tf1, tf0, tf1);

    // ---- x first block
    f32x4 aX = MFMA(AW(12), Bx0, zero4);
    aX = MFMA(AW(13), Byz, aX);
    aX = MFMA(AW(14), Bt0, aX);

    // ---- 3 x iterations
    u32 xh0, xh1, xl0, xl1;
#pragma unroll
    for (int i = 0; i < 3; ++i) {
      act_sp(aX, g, xh0, xh1, xl0, xl1);
      s8v ax = AW(15+5*i);
      aX = MFMA(ax, mkfrag(xh0, xh1, xh0, xh1), zero4);
      aX = MFMA(ax, mkfrag(xl0, xl1, 0u, 0u), aX);
      aX = MFMA(AW(16+5*i), Bx0, aX);
      s8v axy = AW(17+5*i);
      aX = MFMA(axy, FyH, aX);
      aX = MFMA(axy, FyL, aX);
      aX = MFMA(AW(18+5*i), Fz, aX);
      aX = MFMA(AW(19+5*i), Ft, aX);
    }

    // ---- final linear
    act_sp(aX, g, xh0, xh1, xl0, xl1);
    s8v af = AW(30);
    f32x4 aO = MFMA(af, mkfrag(xh0, xh1, xh0, xh1), zero4);
    aO = MFMA(af, mkfrag(xl0, xl1, 0u, 0u), aO);

    // ---- coalesced store via tiny LDS transpose
    *(f32x4*)(&olds[w][c*20 + 4*g]) = aO;
    float* orow = outg + (size_t)T * 240;
#pragma unroll
    for (int jj = 0; jj < 4; ++jj)
      if (oon[jj]) orow[lane + 64*jj] = olds[w][oidx[jj]];
  }
#undef AW
}

extern "C" void kernel_launch(void* const* d_in, const int* in_sizes, int n_in,
                              void* d_out, int out_size, void* d_ws, size_t ws_size,
                              hipStream_t stream) {
  P p;
  p.yW0 = (const float*)d_in[4];  p.yWs = (const float*)d_in[5];  p.yb  = (const float*)d_in[6];
  p.zW0 = (const float*)d_in[7];  p.zWs = (const float*)d_in[8];  p.zb  = (const float*)d_in[9];
  p.tW0 = (const float*)d_in[10]; p.tWs = (const float*)d_in[11]; p.tb  = (const float*)d_in[12];
  p.x0W = (const float*)d_in[13]; p.x0b = (const float*)d_in[14];
  p.y0W = (const float*)d_in[15]; p.y0b = (const float*)d_in[16];
  p.z0W = (const float*)d_in[17]; p.z0b = (const float*)d_in[18];
  p.t0W = (const float*)d_in[19]; p.t0b = (const float*)d_in[20];
  p.xWs = (const float*)d_in[21]; p.xb  = (const float*)d_in[22];
  p.xsW = (const float*)d_in[23]; p.xsb = (const float*)d_in[24];
  p.xyW = (const float*)d_in[25]; p.xyb = (const float*)d_in[26];
  p.xzW = (const float*)d_in[27]; p.xzb = (const float*)d_in[28];
  p.xtW = (const float*)d_in[29]; p.xtb = (const float*)d_in[30];
  p.fW  = (const float*)d_in[31]; p.fb  = (const float*)d_in[32];

  u32* Abuf = (u32*)d_ws;
  prep_kernel<<<8, 256, 0, stream>>>(p, Abuf);

  const float* x0 = (const float*)d_in[0];
  const float* y0 = (const float*)d_in[1];
  const float* z0 = (const float*)d_in[2];
  const float* t0 = (const float*)d_in[3];

  const int n = in_sizes[0] / 16;          // 1048576 rows
  const int blocks = n / 512;              // 8 waves x 4 tiles x 16 rows
  isnn_fwd<<<blocks, 512, 0, stream>>>(x0, y0, z0, t0, Abuf, (float*)d_out);
}